// Round 2
// baseline (410.441 us; speedup 1.0000x reference)
//
#include <hip/hip_runtime.h>

// ReactionTerm: y_out[b, inds_1p[r]] += y_in[b, inds_1r[r]] * rates_1st[b, r]
//               y_out[b, inds_2p[r]] += y_in[b, i2r0[r]] * y_in[b, i2r1[r]] * rates_2nd[b, r]
// B=1024, N_SPEC=2048, R1=20000, R2=40000.
//
// R6: same plan as R5 (LDS-staged e-lists to kill the ~100us divergent global
// gather TA serialization; fused single-kernel CSR build), but R5 asked for
// 68.2 KB static LDS in k_main (> 64 KB per-workgroup cap) -> launch failure.
// Fix: CH 5000->4000 => LDS = 8 KB (ys) + 16 KB (rates) + 32 KB (e2) =
// 56.2 KB (2 blocks/CU, same ~50% occupancy as baseline). ptr stored as
// ushort (offsets <= 4000) to keep ws footprint at 461 KB (< proven 499 KB).

#define NSPEC 2048
#define BDIM  1024          // rows
#define R1    20000
#define R2    40000
#define CH    4000          // reactions per chunk (both orders)
#define NCH1  (R1 / CH)     // 5 first-order chunks
#define NCH2  (R2 / CH)     // 10 second-order chunks
#define NCH   (NCH1 + NCH2) // 15

// d_ws layout (bytes):
#define WS_PTR 0            // ushort[NCH*(NSPEC+1)] = 61470 B (rounded 61472)
#define WS_E1  61472        // uint[R1]   = 80000 B  (reactant | local_j<<16)
#define WS_E2  141472       // uint2[R2]  = 320000 B (r0|r1<<16, local_j)
// total 461472 B

// ---------------------------------------------------------------------------
// One block per chunk: LDS histogram -> LDS scan -> LDS-cursor fill.
// No global atomics, no inter-block dependencies, replaces 4 kernels.
// ---------------------------------------------------------------------------
__global__ __launch_bounds__(1024) void k_build(
    const int* __restrict__ inds_1r, const int* __restrict__ inds_1p,
    const int* __restrict__ inds_2r, const int* __restrict__ inds_2p,
    ushort* __restrict__ ptr, uint* __restrict__ e1, uint2* __restrict__ e2)
{
    __shared__ uint cnt[NSPEC];   // counts, then fill cursors
    __shared__ uint part[1024];

    const int c   = blockIdx.x;
    const int tid = threadIdx.x;

    cnt[tid]        = 0u;
    cnt[tid + 1024] = 0u;
    __syncthreads();

    const bool first = (c < NCH1);
    const int  base  = first ? c * CH : (c - NCH1) * CH;
    const int* __restrict__ prod = first ? inds_1p : inds_2p;

    // Histogram of product species for this chunk.
    for (int i = tid; i < CH; i += 1024)
        atomicAdd(&cnt[prod[base + i]], 1u);
    __syncthreads();

    // Exclusive scan of 2048 counts (2 per thread, Hillis-Steele over 1024).
    uint v0 = cnt[2 * tid], v1 = cnt[2 * tid + 1];
    uint tsum = v0 + v1;
    part[tid] = tsum;
    __syncthreads();
    for (int off = 1; off < 1024; off <<= 1) {
        uint x = (tid >= off) ? part[tid - off] : 0u;
        __syncthreads();
        part[tid] += x;
        __syncthreads();
    }
    uint run = part[tid] - tsum;   // exclusive prefix of this thread's pair

    ushort* pb = ptr + c * (NSPEC + 1);
    pb[2 * tid]     = (ushort)run;
    pb[2 * tid + 1] = (ushort)(run + v0);
    cnt[2 * tid]     = run;        // re-purpose as fill cursor
    cnt[2 * tid + 1] = run + v0;
    if (tid == 1023) pb[NSPEC] = (ushort)(run + tsum);   // == CH
    __syncthreads();

    // Fill the product-sorted entry list via LDS cursors.
    if (first) {
        for (int i = tid; i < CH; i += 1024) {
            const int j = base + i;
            const int s = inds_1p[j];
            const uint pos = atomicAdd(&cnt[s], 1u);
            e1[c * CH + pos] = (uint)inds_1r[j] | ((uint)i << 16);
        }
    } else {
        const int c2 = c - NCH1;
        for (int i = tid; i < CH; i += 1024) {
            const int j = base + i;
            const int s = inds_2p[j];
            const uint pos = atomicAdd(&cnt[s], 1u);
            const uint r0  = (uint)inds_2r[2 * j];
            const uint r1_ = (uint)inds_2r[2 * j + 1];
            e2[c2 * CH + pos] = make_uint2(r0 | (r1_ << 16), (uint)i);
        }
    }
}

// ---------------------------------------------------------------------------
// Main: 1 block/row, thread owns 4 species, register accumulation.
// Per chunk stage rates AND e-list in LDS (coalesced float4) -> inner loop is
// all-LDS, zero divergent global gathers, zero atomics.
// ---------------------------------------------------------------------------
#define MBLOCK 512
#define SPT    (NSPEC / MBLOCK)   // 4 species per thread

__global__ __launch_bounds__(MBLOCK) void k_main(
    const float* __restrict__ y_in,
    const float* __restrict__ rates_1st,
    const float* __restrict__ rates_2nd,
    const ushort* __restrict__ ptr,
    const uint*  __restrict__ e1,
    const uint2* __restrict__ e2,
    float*       __restrict__ y_out)
{
    __shared__ float ys[NSPEC];                                    // 8 KB
    __shared__ __align__(16) unsigned char stage[CH * 4 + CH * 8]; // 48 KB
    float* rl  = (float*)stage;                 // CH rates (16 KB)
    uint*  e1c = (uint*) (stage + CH * 4);      // 1st-order entries (16 KB)
    uint2* e2c = (uint2*)(stage + CH * 4);      // 2nd-order entries (32 KB)

    const int b   = blockIdx.x;
    const int tid = threadIdx.x;

    // Stage y row (512 float4 = one per thread).
    {
        const float4* yrow = reinterpret_cast<const float4*>(y_in + (size_t)b * NSPEC);
        reinterpret_cast<float4*>(ys)[tid] = yrow[tid];
    }

    float acc[SPT];
    #pragma unroll
    for (int k = 0; k < SPT; ++k) acc[k] = 0.f;

    for (int c = 0; c < NCH; ++c) {
        const bool first = (c < NCH1);

        // Stage this chunk's rates (coalesced float4 stream).
        const float* rsrc = first
            ? rates_1st + (size_t)b * R1 + c * CH
            : rates_2nd + (size_t)b * R2 + (c - NCH1) * CH;
        const float4* r4 = reinterpret_cast<const float4*>(rsrc);
        for (int i = tid; i < CH / 4; i += MBLOCK)
            reinterpret_cast<float4*>(rl)[i] = r4[i];

        // Stage this chunk's e-list (coalesced; L2-served, shared by all rows).
        if (first) {
            const float4* s4 = reinterpret_cast<const float4*>(e1 + c * CH);
            for (int i = tid; i < CH / 4; i += MBLOCK)          // 1000 x 16B
                reinterpret_cast<float4*>(e1c)[i] = s4[i];
        } else {
            const float4* s4 = reinterpret_cast<const float4*>(e2 + (c - NCH1) * CH);
            for (int i = tid; i < CH / 2; i += MBLOCK)          // 2000 x 16B
                reinterpret_cast<float4*>(e2c)[i] = s4[i];
        }
        __syncthreads();

        const ushort* pb = ptr + c * (NSPEC + 1);
        if (first) {
            #pragma unroll
            for (int k = 0; k < SPT; ++k) {
                const int s = tid + k * MBLOCK;
                const uint beg = pb[s], end = pb[s + 1];
                float a = 0.f;
                for (uint j = beg; j < end; ++j) {
                    const uint e = e1c[j];
                    a += ys[e & 0xFFFFu] * rl[e >> 16];
                }
                acc[k] += a;
            }
        } else {
            #pragma unroll
            for (int k = 0; k < SPT; ++k) {
                const int s = tid + k * MBLOCK;
                const uint beg = pb[s], end = pb[s + 1];
                float a = 0.f;
                for (uint j = beg; j < end; ++j) {
                    const uint2 e = e2c[j];
                    a += ys[e.x & 0xFFFFu] * ys[e.x >> 16] * rl[e.y];
                }
                acc[k] += a;
            }
        }
        __syncthreads();   // before next chunk overwrites the staging buffers
    }

    // Coalesced writeback: thread tid owns species tid + k*MBLOCK.
    #pragma unroll
    for (int k = 0; k < SPT; ++k)
        y_out[(size_t)b * NSPEC + tid + k * MBLOCK] = acc[k];
}

extern "C" void kernel_launch(void* const* d_in, const int* in_sizes, int n_in,
                              void* d_out, int out_size, void* d_ws, size_t ws_size,
                              hipStream_t stream) {
    const float* y_in      = (const float*)d_in[0];
    const float* rates_1st = (const float*)d_in[1];
    const float* rates_2nd = (const float*)d_in[2];
    const int*   inds_1r   = (const int*)d_in[3];
    const int*   inds_1p   = (const int*)d_in[4];
    const int*   inds_2r   = (const int*)d_in[5];
    const int*   inds_2p   = (const int*)d_in[6];
    float*       y_out     = (float*)d_out;

    char* ws = (char*)d_ws;
    ushort* ptr = (ushort*)(ws + WS_PTR);
    uint*   e1  = (uint*)  (ws + WS_E1);
    uint2*  e2  = (uint2*) (ws + WS_E2);

    // Build CSR every call (d_ws is re-poisoned) — single fused kernel.
    k_build<<<NCH, 1024, 0, stream>>>(inds_1r, inds_1p, inds_2r, inds_2p,
                                      ptr, e1, e2);
    k_main<<<BDIM, MBLOCK, 0, stream>>>(y_in, rates_1st, rates_2nd,
                                        ptr, e1, e2, y_out);
}

// Round 3
// 341.774 us; speedup vs baseline: 1.2009x; 1.2009x over previous
//
#include <hip/hip_runtime.h>

// ReactionTerm: y_out[b, inds_1p[r]] += y_in[b, inds_1r[r]] * rates_1st[b, r]
//               y_out[b, inds_2p[r]] += y_in[b, i2r0[r]] * y_in[b, i2r1[r]] * rates_2nd[b, r]
// B=1024, N_SPEC=2048, R1=20000, R2=40000.
//
// R7 post-mortem of R6: moving e-lists to LDS didn't help (190->207us); no
// pipe saturated (VALU 22%, HBM 8%, occ 47%). Diagnosis: wave divergence in
// the CSR loop — per-(chunk,species) counts ~Poisson(2), wave executes
// max(count)~6.5 vs mean 1.95 => ~30% lane efficiency, inflating LDS+VALU 3x.
// Fix: (a) two-phase chunks: phase A computes tl[i]=ys*ys*rate uniformly
// (coalesced rates/inds from global, no rl staging); phase B accumulates
// acc += tl[e] where e is a 16-bit local index (tiny loop body).
// (b) k_build counting-sorts species by per-chunk count; phase B assigns
// consecutive sorted RANKS to lanes => trip-count spread <=1 within a wave
// (~97% efficiency). accl[] in LDS (exclusive owner per chunk, no atomics).
// LDS 40KB -> 4 blocks/CU = 32 waves = 100% occupancy.

#define NSPEC 2048
#define BDIM  1024          // rows
#define R1    20000
#define R2    40000
#define CH    4000          // reactions per chunk
#define NCH1  (R1 / CH)     // 5 first-order chunks
#define NCH2  (R2 / CH)     // 10 second-order chunks
#define NCH   (NCH1 + NCH2) // 15

// d_ws layout (bytes):
#define WS_PTRR 0                           // uint[NCH*NSPEC]   = 122880 B (beg | cnt<<16, by rank)
#define WS_PERM (NCH * NSPEC * 4)           // ushort[NCH*NSPEC] =  61440 B (rank -> species)
#define WS_E    (WS_PERM + NCH * NSPEC * 2) // ushort[NCH*CH]    = 120000 B (local reaction idx)
// total 304320 B

// ---------------------------------------------------------------------------
// One block per chunk: LDS histogram -> scan -> CSR fill -> counting sort of
// species by count (descending) -> perm + rank-indexed {beg,cnt}.
// ---------------------------------------------------------------------------
__global__ __launch_bounds__(1024) void k_build(
    const int* __restrict__ inds_1p, const int* __restrict__ inds_2p,
    uint* __restrict__ ptrr, ushort* __restrict__ perm, ushort* __restrict__ e)
{
    __shared__ uint cnt[NSPEC];   // hist, then fill cursors
    __shared__ uint part[1024];
    __shared__ uint h2[64];       // histogram of counts (clamped)
    __shared__ uint off[64];      // descending-order cursors

    const int c   = blockIdx.x;
    const int tid = threadIdx.x;

    cnt[tid] = 0u; cnt[tid + 1024] = 0u;
    __syncthreads();

    const bool first = (c < NCH1);
    const int* __restrict__ prod = first ? (inds_1p + c * CH)
                                         : (inds_2p + (c - NCH1) * CH);

    for (int i = tid; i < CH; i += 1024)
        atomicAdd(&cnt[prod[i]], 1u);
    __syncthreads();

    // Exclusive scan of 2048 counts (2 per thread, Hillis-Steele over 1024).
    uint v0 = cnt[2 * tid], v1 = cnt[2 * tid + 1];
    uint tsum = v0 + v1;
    part[tid] = tsum;
    __syncthreads();
    for (int o = 1; o < 1024; o <<= 1) {
        uint x = (tid >= o) ? part[tid - o] : 0u;
        __syncthreads();
        part[tid] += x;
        __syncthreads();
    }
    const uint run  = part[tid] - tsum;
    const uint beg0 = run, beg1 = run + v0;
    cnt[2 * tid]     = beg0;   // fill cursors
    cnt[2 * tid + 1] = beg1;
    if (tid < 64) h2[tid] = 0u;
    __syncthreads();

    // Fill product-sorted entry list (16-bit local reaction indices).
    ushort* ec = e + c * CH;
    for (int i = tid; i < CH; i += 1024) {
        const int s = prod[i];
        const uint pos = atomicAdd(&cnt[s], 1u);
        ec[pos] = (ushort)i;
    }
    // Histogram of per-species counts (separate array; same barrier interval).
    const uint b0 = min(v0, 63u), b1 = min(v1, 63u);
    atomicAdd(&h2[b0], 1u);
    atomicAdd(&h2[b1], 1u);
    __syncthreads();

    if (tid == 0) {            // descending-count bucket offsets
        uint a = 0;
        for (int v = 63; v >= 0; --v) { off[v] = a; a += h2[v]; }
    }
    __syncthreads();

    const uint r0 = atomicAdd(&off[b0], 1u);
    const uint r1 = atomicAdd(&off[b1], 1u);
    perm[c * NSPEC + r0] = (ushort)(2 * tid);
    perm[c * NSPEC + r1] = (ushort)(2 * tid + 1);
    ptrr[c * NSPEC + r0] = beg0 | (v0 << 16);
    ptrr[c * NSPEC + r1] = beg1 | (v1 << 16);
}

// ---------------------------------------------------------------------------
// Main: 1 block/row. Per chunk: phase A computes tl[] uniformly (coalesced
// global inds+rates, LDS ys gathers); phase B accumulates over rank-sorted
// CSR slices (trip counts ~equal within a wave) into LDS accl[].
// ---------------------------------------------------------------------------
#define MBLOCK 512

__global__ __launch_bounds__(MBLOCK, 8) void k_main(
    const float* __restrict__ y_in,
    const float* __restrict__ rates_1st,
    const float* __restrict__ rates_2nd,
    const int*   __restrict__ inds_1r,
    const int*   __restrict__ inds_2r,
    const uint*  __restrict__ ptrr,
    const ushort* __restrict__ perm,
    const ushort* __restrict__ e,
    float*       __restrict__ y_out)
{
    __shared__ float  ys[NSPEC];    //  8 KB
    __shared__ float  accl[NSPEC];  //  8 KB
    __shared__ float  tl[CH];       // 16 KB
    __shared__ ushort el[CH];       //  8 KB   -> 40 KB total

    const int b   = blockIdx.x;
    const int tid = threadIdx.x;

    ((float4*)ys)[tid] = ((const float4*)(y_in + (size_t)b * NSPEC))[tid];
    accl[tid]        = 0.f;
    accl[tid + 512]  = 0.f;
    accl[tid + 1024] = 0.f;
    accl[tid + 1536] = 0.f;
    __syncthreads();

    for (int c = 0; c < NCH; ++c) {
        // ---- Phase A: per-reaction terms, fully uniform ----
        if (c < NCH1) {
            const int base = c * CH;
            const int4*   iv = (const int4*)  (inds_1r + base);
            const float4* rv = (const float4*)(rates_1st + (size_t)b * R1 + base);
            for (int i = tid; i < CH / 4; i += MBLOCK) {
                const int4   r = iv[i];
                const float4 q = rv[i];
                float4 t;
                t.x = ys[r.x] * q.x;
                t.y = ys[r.y] * q.y;
                t.z = ys[r.z] * q.z;
                t.w = ys[r.w] * q.w;
                ((float4*)tl)[i] = t;
            }
        } else {
            const int base = (c - NCH1) * CH;
            const uint4*  iv = (const uint4*) (inds_2r + 2 * base);  // 2 reactions
            const float2* rv = (const float2*)(rates_2nd + (size_t)b * R2 + base);
            for (int i = tid; i < CH / 2; i += MBLOCK) {
                const uint4  r = iv[i];
                const float2 q = rv[i];
                float2 t;
                t.x = ys[r.x] * ys[r.y] * q.x;
                t.y = ys[r.z] * ys[r.w] * q.y;
                ((float2*)tl)[i] = t;
            }
        }
        // Stage entry list (4000 ushort = 500 uint4, coalesced, L1-hot).
        {
            const uint4* sv = (const uint4*)(e + c * CH);
            for (int i = tid; i < (CH * 2) / 16; i += MBLOCK)
                ((uint4*)el)[i] = sv[i];
        }
        __syncthreads();

        // ---- Phase B: rank-balanced CSR accumulate ----
        const uint*   pr = ptrr + c * NSPEC;
        const ushort* pm = perm + c * NSPEC;
        #pragma unroll
        for (int k = 0; k < 4; ++k) {
            const int  rank = k * MBLOCK + tid;
            const uint bc   = pr[rank];       // coalesced b32
            const int  s    = pm[rank];       // coalesced b16
            uint j = bc & 0xFFFFu;
            uint n = bc >> 16;
            float a = 0.f;
            for (; n > 0; --n, ++j) a += tl[el[j]];
            accl[s] += a;                     // exclusive owner of s this chunk
        }
        __syncthreads();   // before next chunk overwrites tl/el
    }

    ((float4*)(y_out + (size_t)b * NSPEC))[tid] = ((const float4*)accl)[tid];
}

extern "C" void kernel_launch(void* const* d_in, const int* in_sizes, int n_in,
                              void* d_out, int out_size, void* d_ws, size_t ws_size,
                              hipStream_t stream) {
    const float* y_in      = (const float*)d_in[0];
    const float* rates_1st = (const float*)d_in[1];
    const float* rates_2nd = (const float*)d_in[2];
    const int*   inds_1r   = (const int*)d_in[3];
    const int*   inds_1p   = (const int*)d_in[4];
    const int*   inds_2r   = (const int*)d_in[5];
    const int*   inds_2p   = (const int*)d_in[6];
    float*       y_out     = (float*)d_out;

    char* ws = (char*)d_ws;
    uint*   ptrr = (uint*)  (ws + WS_PTRR);
    ushort* perm = (ushort*)(ws + WS_PERM);
    ushort* e    = (ushort*)(ws + WS_E);

    // Build rank-sorted CSR every call (d_ws is re-poisoned).
    k_build<<<NCH, 1024, 0, stream>>>(inds_1p, inds_2p, ptrr, perm, e);
    k_main<<<BDIM, MBLOCK, 0, stream>>>(y_in, rates_1st, rates_2nd,
                                        inds_1r, inds_2r, ptrr, perm, e, y_out);
}

// Round 4
// 331.831 us; speedup vs baseline: 1.2369x; 1.0300x over previous
//
#include <hip/hip_runtime.h>

// ReactionTerm: y_out[b, inds_1p[r]] += y_in[b, inds_1r[r]] * rates_1st[b, r]
//               y_out[b, inds_2p[r]] += y_in[b, i2r0[r]] * y_in[b, i2r1[r]] * rates_2nd[b, r]
// B=1024, N_SPEC=2048, R1=20000, R2=40000.
//
// R8: R7 confirmed divergence was the cost (207->135us, occ 87%). Remaining
// bottleneck: LDS pipe ~63% busy (115k issue + 89k conflict cyc/CU). The el
// round-trip is the reducible part: phase B did 2 LDS reads/entry (el then
// random tl). Fix: k_build emits each reaction's CSR POSITION; phase A writes
// tl[pos] directly (scattered write replaces B's random read 1:1), phase B
// reads tl[beg..beg+n) contiguous-per-lane -> 1 read/entry, el+staging gone
// (-8KB LDS, ~-1050 wave-ops/block). CH 4000->5000 (12 chunks: -20% accl RMW
// and barriers). ptrr packs beg|cnt<<13|s<<21 (perm array gone). 1st-order
// stream packs r|pos<<11. LDS 36.4KB -> 4 blocks/CU = 32 waves.

#define NSPEC 2048
#define BDIM  1024          // rows
#define R1    20000
#define R2    40000
#define CH    5000          // reactions per chunk
#define NCH1  (R1 / CH)     // 4 first-order chunks
#define NCH2  (R2 / CH)     // 8 second-order chunks
#define NCH   (NCH1 + NCH2) // 12

// d_ws layout (bytes):
#define WS_PTRR 0                            // uint[NCH*NSPEC] = 98304 B (beg|cnt<<13|s<<21, by rank)
#define WS_E1P  (NCH * NSPEC * 4)            // uint[R1]   = 80000 B (r | csrpos<<11, original order)
#define WS_CSR2 (WS_E1P + R1 * 4)            // ushort[R2] = 80000 B (csrpos, original order)
// total 258304 B

// ---------------------------------------------------------------------------
// One block per chunk: LDS histogram -> scan -> csr-position assignment (by
// original reaction index, coalesced writes) -> count-sorted rank packing.
// ---------------------------------------------------------------------------
__global__ __launch_bounds__(1024) void k_build(
    const int* __restrict__ inds_1r,
    const int* __restrict__ inds_1p, const int* __restrict__ inds_2p,
    uint* __restrict__ ptrr, uint* __restrict__ e1p, ushort* __restrict__ csr2)
{
    __shared__ uint cnt[NSPEC];   // hist, then fill cursors
    __shared__ uint part[1024];
    __shared__ uint h2[64];       // histogram of counts (clamped)
    __shared__ uint off[64];      // descending-order rank cursors

    const int c   = blockIdx.x;
    const int tid = threadIdx.x;

    cnt[tid] = 0u; cnt[tid + 1024] = 0u;
    __syncthreads();

    const bool first = (c < NCH1);
    const int  base  = first ? c * CH : (c - NCH1) * CH;
    const int* __restrict__ prod = first ? (inds_1p + base) : (inds_2p + base);

    for (int i = tid; i < CH; i += 1024)
        atomicAdd(&cnt[prod[i]], 1u);
    __syncthreads();

    // Exclusive scan of 2048 counts (2 per thread, Hillis-Steele over 1024).
    uint v0 = cnt[2 * tid], v1 = cnt[2 * tid + 1];
    uint tsum = v0 + v1;
    part[tid] = tsum;
    __syncthreads();
    for (int o = 1; o < 1024; o <<= 1) {
        uint x = (tid >= o) ? part[tid - o] : 0u;
        __syncthreads();
        part[tid] += x;
        __syncthreads();
    }
    const uint run  = part[tid] - tsum;
    const uint beg0 = run, beg1 = run + v0;
    cnt[2 * tid]     = beg0;   // fill cursors
    cnt[2 * tid + 1] = beg1;
    if (tid < 64) h2[tid] = 0u;
    __syncthreads();

    // Assign CSR positions; write by ORIGINAL reaction index (coalesced).
    if (first) {
        for (int i = tid; i < CH; i += 1024) {
            const int s = prod[i];
            const uint pos = atomicAdd(&cnt[s], 1u);
            e1p[c * CH + i] = (uint)inds_1r[base + i] | (pos << 11);
        }
    } else {
        for (int i = tid; i < CH; i += 1024) {
            const int s = prod[i];
            const uint pos = atomicAdd(&cnt[s], 1u);
            csr2[base + i] = (ushort)pos;
        }
    }
    // Histogram of per-species counts (for balanced rank assignment).
    const uint b0 = min(v0, 63u), b1 = min(v1, 63u);
    atomicAdd(&h2[b0], 1u);
    atomicAdd(&h2[b1], 1u);
    __syncthreads();

    if (tid == 0) {            // descending-count bucket offsets
        uint a = 0;
        for (int v = 63; v >= 0; --v) { off[v] = a; a += h2[v]; }
    }
    __syncthreads();

    const uint r0 = atomicAdd(&off[b0], 1u);
    const uint r1 = atomicAdd(&off[b1], 1u);
    // pack: beg[12:0] | cnt[20:13] | species[31:21]
    ptrr[c * NSPEC + r0] = beg0 | (min(v0, 255u) << 13) | ((uint)(2 * tid) << 21);
    ptrr[c * NSPEC + r1] = beg1 | (min(v1, 255u) << 13) | ((uint)(2 * tid + 1) << 21);
}

// ---------------------------------------------------------------------------
// Main: 1 block/row. Phase A: uniform term computation, scattered tl[pos]
// write (global streams all coalesced). Phase B: rank-balanced contiguous
// tl range sum (1 LDS read per entry), accl RMW once per species per chunk.
// ---------------------------------------------------------------------------
#define MBLOCK 512

__global__ __launch_bounds__(MBLOCK, 8) void k_main(
    const float* __restrict__ y_in,
    const float* __restrict__ rates_1st,
    const float* __restrict__ rates_2nd,
    const int*   __restrict__ inds_2r,
    const uint*  __restrict__ ptrr,
    const uint*  __restrict__ e1p,
    const ushort* __restrict__ csr2,
    float*       __restrict__ y_out)
{
    __shared__ float ys[NSPEC];    //  8 KB
    __shared__ float accl[NSPEC];  //  8 KB
    __shared__ float tl[CH];       // 20 KB  -> 36.4 KB total, 4 blocks/CU

    const int b   = blockIdx.x;
    const int tid = threadIdx.x;

    ((float4*)ys)[tid] = ((const float4*)(y_in + (size_t)b * NSPEC))[tid];
    ((float4*)accl)[tid] = make_float4(0.f, 0.f, 0.f, 0.f);
    __syncthreads();

    for (int c = 0; c < NCH; ++c) {
        // ---- Phase A: per-reaction terms -> tl[csr position] ----
        if (c < NCH1) {
            const uint4*  ev = (const uint4*) (e1p + c * CH);
            const float4* rv = (const float4*)(rates_1st + (size_t)b * R1 + c * CH);
            for (int i = tid; i < CH / 4; i += MBLOCK) {   // 1250 iters
                const uint4  e = ev[i];
                const float4 q = rv[i];
                tl[e.x >> 11] = ys[e.x & 2047u] * q.x;
                tl[e.y >> 11] = ys[e.y & 2047u] * q.y;
                tl[e.z >> 11] = ys[e.z & 2047u] * q.z;
                tl[e.w >> 11] = ys[e.w & 2047u] * q.w;
            }
        } else {
            const int c2 = c - NCH1;
            const uint4*   iv = (const uint4*)  (inds_2r + 2 * (c2 * CH));
            const float4*  rv = (const float4*) (rates_2nd + (size_t)b * R2 + c2 * CH);
            const ushort4* pv = (const ushort4*)(csr2 + c2 * CH);
            for (int i = tid; i < CH / 4; i += MBLOCK) {   // 1250 iters, 4 reactions
                const uint4   ia = iv[2 * i];
                const uint4   ib = iv[2 * i + 1];
                const float4  q  = rv[i];
                const ushort4 p  = pv[i];
                tl[p.x] = ys[ia.x] * ys[ia.y] * q.x;
                tl[p.y] = ys[ia.z] * ys[ia.w] * q.y;
                tl[p.z] = ys[ib.x] * ys[ib.y] * q.z;
                tl[p.w] = ys[ib.z] * ys[ib.w] * q.w;
            }
        }
        __syncthreads();

        // ---- Phase B: rank-balanced contiguous range sums ----
        const uint* pr = ptrr + c * NSPEC;
        #pragma unroll
        for (int k = 0; k < 4; ++k) {
            const uint v   = pr[k * MBLOCK + tid];   // coalesced b32
            uint       j   = v & 0x1FFFu;
            uint       n   = (v >> 13) & 0xFFu;
            const uint s   = v >> 21;
            float a = 0.f;
            for (; n > 0; --n, ++j) a += tl[j];
            accl[s] += a;                            // exclusive owner this chunk
        }
        __syncthreads();   // before next chunk overwrites tl
    }

    ((float4*)(y_out + (size_t)b * NSPEC))[tid] = ((const float4*)accl)[tid];
}

extern "C" void kernel_launch(void* const* d_in, const int* in_sizes, int n_in,
                              void* d_out, int out_size, void* d_ws, size_t ws_size,
                              hipStream_t stream) {
    const float* y_in      = (const float*)d_in[0];
    const float* rates_1st = (const float*)d_in[1];
    const float* rates_2nd = (const float*)d_in[2];
    const int*   inds_1r   = (const int*)d_in[3];
    const int*   inds_1p   = (const int*)d_in[4];
    const int*   inds_2r   = (const int*)d_in[5];
    const int*   inds_2p   = (const int*)d_in[6];
    float*       y_out     = (float*)d_out;

    char* ws = (char*)d_ws;
    uint*   ptrr = (uint*)  (ws + WS_PTRR);
    uint*   e1p  = (uint*)  (ws + WS_E1P);
    ushort* csr2 = (ushort*)(ws + WS_CSR2);

    // Build CSR metadata every call (d_ws is re-poisoned).
    k_build<<<NCH, 1024, 0, stream>>>(inds_1r, inds_1p, inds_2p, ptrr, e1p, csr2);
    k_main<<<BDIM, MBLOCK, 0, stream>>>(y_in, rates_1st, rates_2nd, inds_2r,
                                        ptrr, e1p, csr2, y_out);
}